// Round 1
// 228.102 us; speedup vs baseline: 1.0579x; 1.0579x over previous
//
#include <hip/hip_runtime.h>
#include <hip/hip_bf16.h>

// Problem constants (HGCN_84980222918800)
#define NNZV      400000
#define NUM_EDGES 20000
#define NUM_NODES 40000   // B*N
#define NPART     8       // build privatization (XCD-locality heuristic via blockIdx&7)
#define EC8       20      // per-partition edge members cap (Pois(2.5); P(>=20)~1e-13)
#define NC8       14      // per-partition node edges cap  (Pois(1.25); P(>=14)~1e-12)
#define CVT_BLOCKS 5000   // 40000*256 halfwords / (256 thr * 8/lane); 5000%8==0 keeps
                          // build's blockIdx&7 -> XCD mapping intact after fusion
// per-node / per-edge feature block = 256 values; x layout [f*4+t], edge_x t-major [t*64+f]

// Pipeline: out = relu( [D^-1 H B^-1 (H^T X)] W + b )
//   cvt+build: (fused launch, disjoint block ranges — convert streams while build's
//              atomics are latency-bound)
//              convert : x (f32|bf16) -> fp16 xh16, same layout. Halves the 400K-row
//                        gather traffic in edge_agg (was 1KB f32 rows = ~410MB of
//                        L3-bound requests; now 512B).
//              build   : 8-way privatized histogram + fixed-stride u16 adjacency
//   edge_agg : per-edge mean of member xh16 rows -> edge_x fp16 (t-major)
//   node_gemm: per-node sum of edge rows, D = sum hewi[e] computed in-loop,
//              * D^-1 -> LDS A-tile (fp16) -> MFMA f16 x W -> out
// fp16 (not bf16) intermediates: 3 extra mantissa bits cut the two intermediate
// roundings ~8x — absmax was sitting exactly at 0.015625 with bf16.

typedef _Float16 v8h __attribute__((ext_vector_type(8)));  // 8 x fp16 (4 VGPRs)
typedef float v4f  __attribute__((ext_vector_type(4)));    // MFMA acc

__device__ __forceinline__ float bf2f(unsigned short u) {
    return __uint_as_float(((unsigned)u) << 16);
}
__device__ __forceinline__ unsigned short f2bf(float f) {
    __hip_bfloat16 h = __float2bfloat16(f);   // RNE
    return *(unsigned short*)&h;
}
__device__ __forceinline__ unsigned short f2h(float f) {
    _Float16 h = (_Float16)f;                 // v_cvt_f16_f32, RNE
    return *(unsigned short*)&h;
}
__device__ __forceinline__ float loadf(const void* p, int idx, int isf32) {
    return isf32 ? ((const float*)p)[idx]
                 : bf2f(((const unsigned short*)p)[idx]);
}

// Per-block dtype detection (reads ~1.5KB of L2-hot data; no extra launch).
__device__ __forceinline__ void detect_flags(const int* __restrict__ he,
                                             const unsigned short* __restrict__ xh,
                                             int& is64, int& isf32, int* lflag) {
    const int tid = threadIdx.x;
    if (tid < 2) lflag[tid] = 0;
    __syncthreads();
    if (tid < 64 && he[2 * tid + 1] != 0) atomicOr(&lflag[0], 1);
    {
        float v = bf2f(xh[tid]);                 // first 256 halfwords of x
        if (!(v == v) || v > 1e4f || v < -1e4f) atomicOr(&lflag[1], 1);
    }
    __syncthreads();
    is64  = (lflag[0] == 0);
    isf32 = lflag[1];
}

__device__ __forceinline__ void load_vi_ei(const int* __restrict__ he, int i,
                                           int is64, int& v, int& e) {
    if (is64) { v = he[2 * i]; e = he[2 * NNZV + 2 * i]; }
    else      { v = he[i];     e = he[NNZV + i]; }
}

__device__ __forceinline__ void acc8_h(const int4 u, float* a) {
    union { int4 i; _Float16 h[8]; } q; q.i = u;
    #pragma unroll
    for (int k = 0; k < 8; ++k) a[k] += (float)q.h[k];   // v_cvt_f32_f16
}

// ---- fused: x -> fp16 convert (blocks 0..4999) + build (blocks 5000..) ---------
__global__ void convert_build_kernel(const int* __restrict__ he,
                                     const void* __restrict__ x,
                                     int* __restrict__ ecnt8, int* __restrict__ ncnt8,
                                     unsigned short* __restrict__ elst8,
                                     unsigned short* __restrict__ nlst8,
                                     unsigned short* __restrict__ xh16) {
    __shared__ int lflag[2];
    int is64, isf32;
    detect_flags(he, (const unsigned short*)x, is64, isf32, lflag);

    if (blockIdx.x < CVT_BLOCKS) {               // ---- convert branch ----
        const size_t idx = ((size_t)blockIdx.x * 256 + threadIdx.x) * 8;
        float v[8];
        if (isf32) {
            const float* xf = (const float*)x + idx;
            const float4 u0 = *(const float4*)xf;
            const float4 u1 = *(const float4*)(xf + 4);
            v[0] = u0.x; v[1] = u0.y; v[2] = u0.z; v[3] = u0.w;
            v[4] = u1.x; v[5] = u1.y; v[6] = u1.z; v[7] = u1.w;
        } else {
            const int4 u = *(const int4*)((const unsigned short*)x + idx);
            v[0] = bf2f((unsigned short)((unsigned)u.x & 0xffff));
            v[1] = bf2f((unsigned short)((unsigned)u.x >> 16));
            v[2] = bf2f((unsigned short)((unsigned)u.y & 0xffff));
            v[3] = bf2f((unsigned short)((unsigned)u.y >> 16));
            v[4] = bf2f((unsigned short)((unsigned)u.z & 0xffff));
            v[5] = bf2f((unsigned short)((unsigned)u.z >> 16));
            v[6] = bf2f((unsigned short)((unsigned)u.w & 0xffff));
            v[7] = bf2f((unsigned short)((unsigned)u.w >> 16));
        }
        unsigned short pk[8];
        #pragma unroll
        for (int k = 0; k < 8; ++k) {
            float c = fminf(fmaxf(v[k], -65504.f), 65504.f);  // f16 range guard
            pk[k] = f2h(c);
        }
        *(int4*)(xh16 + idx) = *(int4*)pk;
        return;
    }
    // ---- build branch ----
    const int p = blockIdx.x & (NPART - 1);      // XCD-locality heuristic only
    const int i = (blockIdx.x - CVT_BLOCKS) * 256 + threadIdx.x;
    if (i >= NNZV) return;
    int v, e;
    load_vi_ei(he, i, is64, v, e);
    if ((unsigned)v >= NUM_NODES || (unsigned)e >= NUM_EDGES) return;  // safety
    const int se = atomicAdd(&ecnt8[p * NUM_EDGES + e], 1);
    if (se < EC8) elst8[(size_t)(p * NUM_EDGES + e) * EC8 + se] = (unsigned short)v;
    const int sn = atomicAdd(&ncnt8[p * NUM_NODES + v], 1);
    if (sn < NC8) nlst8[(size_t)(p * NUM_NODES + v) * NC8 + sn] = (unsigned short)e;
}

// ---- edge_agg: edge_x[e][t*64+f] = (1/deg) * sum_{v in e} xh16[v][f*4+t] -------
// one wave per edge; half-wave per member row, 16B/lane (8 fp16), shfl_xor(32)
__global__ void edge_agg_kernel(const unsigned short* __restrict__ xh16,
                                const int* __restrict__ ecnt8,
                                const unsigned short* __restrict__ elst8,
                                unsigned short* __restrict__ edge_x) {
    const int wid = threadIdx.x >> 6, lane = threadIdx.x & 63;
    const int e = blockIdx.x * 4 + wid;
    const int half = lane >> 5, sl = lane & 31;
    int c[NPART], degTot = 0;
    #pragma unroll
    for (int p = 0; p < NPART; ++p) {            // independent L2-hot count loads
        c[p] = ecnt8[p * NUM_EDGES + e];
        degTot += c[p];
    }
    float a[8] = {0.f, 0.f, 0.f, 0.f, 0.f, 0.f, 0.f, 0.f};
    #pragma unroll
    for (int p = 0; p < NPART; ++p) {
        const int cc = c[p] < EC8 ? c[p] : EC8;
        const unsigned short* lst = elst8 + (size_t)(p * NUM_EDGES + e) * EC8;
        for (int j = half; j < cc; j += 2) {
            const int v = (int)lst[j];
            const int4 u = *(const int4*)(xh16 + (size_t)v * 256 + sl * 8);
            acc8_h(u, a);
        }
    }
    #pragma unroll
    for (int k = 0; k < 8; ++k) a[k] += __shfl_xor(a[k], 32);
    const float binv = degTot > 0 ? 1.f / (float)degTot : 0.f;
    if (lane < 32) {
        // lane holds halfwords h = sl*8+k of x-layout: f = 2*sl + (k>>2), t = k&3
        unsigned short* row = edge_x + (size_t)e * 256;
        #pragma unroll
        for (int t = 0; t < 4; ++t) {
            unsigned pk = (unsigned)f2h(a[t] * binv)
                        | ((unsigned)f2h(a[4 + t] * binv) << 16);
            *(unsigned*)(row + t * 64 + sl * 2) = pk;   // t-major transpose
        }
    }
}

// ---- node_gemm: per wave 4 nodes -> 16x64 A-tile -> 16x16x32 f16 MFMA x W ------
// D[v] = sum_{e ni v} hewi[e] computed in the gather loop (no global atomics)
__global__ __launch_bounds__(256) void node_gemm_kernel(
        const int* __restrict__ he, const unsigned short* __restrict__ xdet,
        const unsigned short* __restrict__ edge_x, const void* __restrict__ hewi,
        const int* __restrict__ ncnt8, const unsigned short* __restrict__ nlst8,
        const void* __restrict__ W, const void* __restrict__ bias,
        void* __restrict__ out) {
    __shared__ __align__(16) unsigned short wt[64 * 72];        // W^T [o][f], pad 72
    __shared__ __align__(16) unsigned short atile[4][16 * 72];  // per-wave A tile
    __shared__ float lbias[64];
    __shared__ int lflag[2];
    int is64, isf32;
    detect_flags(he, xdet, is64, isf32, lflag);
    const int tid = threadIdx.x, wid = tid >> 6, lane = tid & 63;
    const int quad = lane >> 4, l15 = lane & 15;
    const int half = lane >> 5, sl = lane & 31;

    #pragma unroll
    for (int k = 0; k < 16; ++k) {                // stage W^T once per block (fp16)
        int idx = tid + k * 256;                  // f = idx>>6, o = idx&63
        wt[(idx & 63) * 72 + (idx >> 6)] = f2h(loadf(W, idx, isf32));
    }
    if (tid < 64) lbias[tid] = loadf(bias, tid, isf32);

    const int tile = blockIdx.x * 4 + wid;        // 16 A-rows = 4 nodes
    for (int r = 0; r < 4; ++r) {
        const int v = tile * 4 + r;
        int c[NPART];
        #pragma unroll
        for (int p = 0; p < NPART; ++p) c[p] = ncnt8[p * NUM_NODES + v];
        float a[8] = {0.f, 0.f, 0.f, 0.f, 0.f, 0.f, 0.f, 0.f};
        float dsum = 0.f;
        #pragma unroll
        for (int p = 0; p < NPART; ++p) {
            const int cc = c[p] < NC8 ? c[p] : NC8;
            const unsigned short* lst = nlst8 + (size_t)(p * NUM_NODES + v) * NC8;
            for (int j = half; j < cc; j += 2) {
                const int e = (int)lst[j];
                const int4 u = *(const int4*)(edge_x + (size_t)e * 256 + sl * 8);
                acc8_h(u, a);
                if (sl == 0) dsum += loadf(hewi, e, isf32);   // once per member
            }
        }
        #pragma unroll
        for (int k = 0; k < 8; ++k) a[k] += __shfl_xor(a[k], 32);
        dsum += __shfl_xor(dsum, 32);             // lane0 now holds full sum
        const float d = __shfl(dsum, 0);
        const float s = d > 0.f ? 1.f / d : 0.f;  // D^-1 folded in (GEMM linear)
        if (lane < 32) {
            // t-major row halfwords h=sl*8+k: t = sl>>3, f = (sl&7)*8 + k
            unsigned short pk[8];
            #pragma unroll
            for (int k = 0; k < 8; ++k) pk[k] = f2h(a[k] * s);
            *(int4*)&atile[wid][(r * 4 + (sl >> 3)) * 72 + (sl & 7) * 8] =
                *(int4*)pk;
        }
    }
    __syncthreads();

    v8h bfr[4][2];                                // B frags: lane holds B[k][n]
    #pragma unroll
    for (int j = 0; j < 4; ++j)
        #pragma unroll
        for (int kk = 0; kk < 2; ++kk)
            bfr[j][kk] = *(v8h*)&wt[(j * 16 + l15) * 72 + quad * 8 + kk * 32];
    // A frags: lane holds A[m=lane&15][k=quad*8+j]
    v8h af0 = *(v8h*)&atile[wid][l15 * 72 + quad * 8];
    v8h af1 = *(v8h*)&atile[wid][l15 * 72 + quad * 8 + 32];

    const int node = tile * 4 + quad;             // C row = quad*4+reg -> t=reg
    #pragma unroll
    for (int j = 0; j < 4; ++j) {
        v4f acc = {0.f, 0.f, 0.f, 0.f};
        acc = __builtin_amdgcn_mfma_f32_16x16x32_f16(af0, bfr[j][0], acc, 0, 0, 0);
        acc = __builtin_amdgcn_mfma_f32_16x16x32_f16(af1, bfr[j][1], acc, 0, 0, 0);
        const int o = j * 16 + l15;
        const float bv = lbias[o];
        float r0 = acc[0] + bv, r1 = acc[1] + bv, r2 = acc[2] + bv, r3 = acc[3] + bv;
        r0 = r0 > 0.f ? r0 : 0.f; r1 = r1 > 0.f ? r1 : 0.f;
        r2 = r2 > 0.f ? r2 : 0.f; r3 = r3 > 0.f ? r3 : 0.f;
        if (isf32) {
            float4 f4 = { r0, r1, r2, r3 };       // out[node][o][t], t=0..3
            *(float4*)((float*)out + (size_t)node * 256 + o * 4) = f4;
        } else {
            ushort4 pk = { f2bf(r0), f2bf(r1), f2bf(r2), f2bf(r3) };
            *(ushort4*)((unsigned short*)out + (size_t)node * 256 + o * 4) = pk;
        }
    }
}

extern "C" void kernel_launch(void* const* d_in, const int* in_sizes, int n_in,
                              void* d_out, int out_size, void* d_ws, size_t ws_size,
                              hipStream_t stream) {
    const void* x    = d_in[0];
    const int*  he   = (const int*)d_in[1];   // [2,NNZ] int32 or int64 (detected)
    const void* hewi = d_in[2];
    const void* W    = d_in[3];
    const void* bias = d_in[4];

    // ---- workspace layout (word offsets); harness provides >= 102.6MB ----------
    float* ws = (float*)d_ws;
    unsigned short* edge_x = (unsigned short*)ws;            // 5.12M hw = 2,560,000 w
    int*   ecnt8 = (int*)(ws + 2560000);                     //   160,000 w (8x20000)
    int*   ncnt8 = (int*)(ws + 2720000);                     //   320,000 w (8x40000)
    unsigned short* elst8 = (unsigned short*)(ws + 3040000); // 3.2M hw = 1,600,000 w
    unsigned short* nlst8 = (unsigned short*)(ws + 4640000); // 4.48M hw = 2,240,000 w
    unsigned short* xh16  = (unsigned short*)(ws + 6880000); // 10.24M hw = 5,120,000 w
    if (ws_size < (size_t)12000000 * 4) return;              // 48MB; clean signal

    // zero privatized counters (contiguous 480,000 words)
    hipMemsetAsync(ecnt8, 0, (size_t)480000 * 4, stream);

    convert_build_kernel<<<CVT_BLOCKS + (NNZV + 255) / 256, 256, 0, stream>>>(
        he, x, ecnt8, ncnt8, elst8, nlst8, xh16);
    edge_agg_kernel<<<NUM_EDGES / 4, 256, 0, stream>>>(
        xh16, ecnt8, elst8, edge_x);
    node_gemm_kernel<<<NUM_NODES / 16, 256, 0, stream>>>(
        he, (const unsigned short*)x, edge_x, hewi, ncnt8, nlst8, W, bias, d_out);
}

// Round 2
// 224.407 us; speedup vs baseline: 1.0753x; 1.0165x over previous
//
#include <hip/hip_runtime.h>
#include <hip/hip_bf16.h>

// Problem constants (HGCN_84980222918800)
#define NNZV      400000
#define NUM_EDGES 20000
#define NUM_NODES 40000   // B*N
#define NPART     8       // build privatization (XCD-locality heuristic via blockIdx&7)
#define EC8       20      // per-partition edge members cap (Pois(2.5); P(>=20)~1e-13)
#define NC8       14      // per-partition node edges cap  (Pois(1.25); P(>=14)~1e-12)
#define ECT       64      // compact edge list cap (Pois(20); P(>=64) ~ 1e-18)
#define NCT       32      // compact node list cap (Pois(10); P(>=32) ~ 1e-10)
#define CVT_BLOCKS 5000   // 40000*256 halfwords / (256 thr * 8/lane); 5000%8==0 keeps
                          // build's blockIdx&7 -> XCD mapping intact after fusion
// per-node / per-edge feature block = 256 values; x layout [f*4+t], edge_x t-major [t*64+f]

// Pipeline: out = relu( [D^-1 H B^-1 (H^T X)] W + b )
//   cvt+build: fused launch (disjoint block ranges): x -> fp16 xh16 convert streams
//              while build's atomics are latency-bound. build = 8-way privatized
//              histogram + fixed-stride u16 adjacency lists.
//   compact  : merge 8 partition lists -> ONE zero-padded contiguous list per
//              edge/node + precompute D^-1 per node. R1 post-mortem: gathers were
//              LATENCY-bound (VALUBusy 25%, FETCH at 1.2TB/s) because the 8-way
//              lists fragment avg-degree-10 nodes into 8 serial (list->row)
//              dependent chains with half the wave idle. Compact lists enable
//              one ushort4 index load -> 4 independent row loads per half-wave.
//   edge_agg : per-edge mean of member xh16 rows -> edge_x fp16 (t-major), 4-deep ILP
//   node_gemm: per-node sum of edge rows * D^-1 (precomputed) -> LDS A-tile (fp16)
//              -> MFMA f16 x W -> out

typedef _Float16 v8h __attribute__((ext_vector_type(8)));  // 8 x fp16 (4 VGPRs)
typedef float v4f  __attribute__((ext_vector_type(4)));    // MFMA acc

__device__ __forceinline__ float bf2f(unsigned short u) {
    return __uint_as_float(((unsigned)u) << 16);
}
__device__ __forceinline__ unsigned short f2bf(float f) {
    __hip_bfloat16 h = __float2bfloat16(f);   // RNE
    return *(unsigned short*)&h;
}
__device__ __forceinline__ unsigned short f2h(float f) {
    _Float16 h = (_Float16)f;                 // v_cvt_f16_f32, RNE
    return *(unsigned short*)&h;
}
__device__ __forceinline__ float loadf(const void* p, int idx, int isf32) {
    return isf32 ? ((const float*)p)[idx]
                 : bf2f(((const unsigned short*)p)[idx]);
}

// Per-block dtype detection (reads ~1.5KB of L2-hot data; no extra launch).
__device__ __forceinline__ void detect_flags(const int* __restrict__ he,
                                             const unsigned short* __restrict__ xh,
                                             int& is64, int& isf32, int* lflag) {
    const int tid = threadIdx.x;
    if (tid < 2) lflag[tid] = 0;
    __syncthreads();
    if (tid < 64 && he[2 * tid + 1] != 0) atomicOr(&lflag[0], 1);
    {
        float v = bf2f(xh[tid]);                 // first 256 halfwords of x
        if (!(v == v) || v > 1e4f || v < -1e4f) atomicOr(&lflag[1], 1);
    }
    __syncthreads();
    is64  = (lflag[0] == 0);
    isf32 = lflag[1];
}

__device__ __forceinline__ void load_vi_ei(const int* __restrict__ he, int i,
                                           int is64, int& v, int& e) {
    if (is64) { v = he[2 * i]; e = he[2 * NNZV + 2 * i]; }
    else      { v = he[i];     e = he[NNZV + i]; }
}

__device__ __forceinline__ void acc8_h(const int4 u, float* a) {
    union { int4 i; _Float16 h[8]; } q; q.i = u;
    #pragma unroll
    for (int k = 0; k < 8; ++k) a[k] += (float)q.h[k];   // v_cvt_f32_f16
}

// ---- fused: x -> fp16 convert (blocks 0..4999) + build (blocks 5000..) ---------
__global__ void convert_build_kernel(const int* __restrict__ he,
                                     const void* __restrict__ x,
                                     int* __restrict__ ecnt8, int* __restrict__ ncnt8,
                                     unsigned short* __restrict__ elst8,
                                     unsigned short* __restrict__ nlst8,
                                     unsigned short* __restrict__ xh16) {
    __shared__ int lflag[2];
    int is64, isf32;
    detect_flags(he, (const unsigned short*)x, is64, isf32, lflag);

    if (blockIdx.x < CVT_BLOCKS) {               // ---- convert branch ----
        const size_t idx = ((size_t)blockIdx.x * 256 + threadIdx.x) * 8;
        float v[8];
        if (isf32) {
            const float* xf = (const float*)x + idx;
            const float4 u0 = *(const float4*)xf;
            const float4 u1 = *(const float4*)(xf + 4);
            v[0] = u0.x; v[1] = u0.y; v[2] = u0.z; v[3] = u0.w;
            v[4] = u1.x; v[5] = u1.y; v[6] = u1.z; v[7] = u1.w;
        } else {
            const int4 u = *(const int4*)((const unsigned short*)x + idx);
            v[0] = bf2f((unsigned short)((unsigned)u.x & 0xffff));
            v[1] = bf2f((unsigned short)((unsigned)u.x >> 16));
            v[2] = bf2f((unsigned short)((unsigned)u.y & 0xffff));
            v[3] = bf2f((unsigned short)((unsigned)u.y >> 16));
            v[4] = bf2f((unsigned short)((unsigned)u.z & 0xffff));
            v[5] = bf2f((unsigned short)((unsigned)u.z >> 16));
            v[6] = bf2f((unsigned short)((unsigned)u.w & 0xffff));
            v[7] = bf2f((unsigned short)((unsigned)u.w >> 16));
        }
        unsigned short pk[8];
        #pragma unroll
        for (int k = 0; k < 8; ++k) {
            float c = fminf(fmaxf(v[k], -65504.f), 65504.f);  // f16 range guard
            pk[k] = f2h(c);
        }
        *(int4*)(xh16 + idx) = *(int4*)pk;
        return;
    }
    // ---- build branch ----
    const int p = blockIdx.x & (NPART - 1);      // XCD-locality heuristic only
    const int i = (blockIdx.x - CVT_BLOCKS) * 256 + threadIdx.x;
    if (i >= NNZV) return;
    int v, e;
    load_vi_ei(he, i, is64, v, e);
    if ((unsigned)v >= NUM_NODES || (unsigned)e >= NUM_EDGES) return;  // safety
    const int se = atomicAdd(&ecnt8[p * NUM_EDGES + e], 1);
    if (se < EC8) elst8[(size_t)(p * NUM_EDGES + e) * EC8 + se] = (unsigned short)v;
    const int sn = atomicAdd(&ncnt8[p * NUM_NODES + v], 1);
    if (sn < NC8) nlst8[(size_t)(p * NUM_NODES + v) * NC8 + sn] = (unsigned short)e;
}

// ---- compact: merge 8 partition lists -> single zero-padded list + D^-1 --------
// gid < 20000: edge e   |  20000 <= gid < 60000: node v (also folds hewi -> dinv)
__global__ __launch_bounds__(256) void compact_kernel(
        const int* __restrict__ he, const unsigned short* __restrict__ xdet,
        const void* __restrict__ hewi,
        const int* __restrict__ ecnt8, const unsigned short* __restrict__ elst8,
        const int* __restrict__ ncnt8, const unsigned short* __restrict__ nlst8,
        unsigned short* __restrict__ ect, unsigned short* __restrict__ nct,
        int* __restrict__ edeg, int* __restrict__ ndeg,
        float* __restrict__ dinv) {
    __shared__ int lflag[2];
    int is64, isf32;
    detect_flags(he, xdet, is64, isf32, lflag);
    (void)is64;
    const int gid = blockIdx.x * 256 + threadIdx.x;
    if (gid < NUM_EDGES) {
        const int e = gid;
        unsigned short* dst = ect + (size_t)e * ECT;
        int d = 0;
        #pragma unroll
        for (int p = 0; p < NPART; ++p) {
            int cc = ecnt8[p * NUM_EDGES + e]; cc = cc < EC8 ? cc : EC8;
            const unsigned short* src = elst8 + (size_t)(p * NUM_EDGES + e) * EC8;
            for (int j = 0; j < cc && d < ECT; ++j) dst[d++] = src[j];
        }
        edeg[e] = d;
        for (int j = d; j < ECT; ++j) dst[j] = 0;   // pad -> row 0 (valid, L2-hot)
    } else if (gid < NUM_EDGES + NUM_NODES) {
        const int v = gid - NUM_EDGES;
        unsigned short* dst = nct + (size_t)v * NCT;
        int d = 0; float dsum = 0.f;
        #pragma unroll
        for (int p = 0; p < NPART; ++p) {
            int cc = ncnt8[p * NUM_NODES + v]; cc = cc < NC8 ? cc : NC8;
            const unsigned short* src = nlst8 + (size_t)(p * NUM_NODES + v) * NC8;
            for (int j = 0; j < cc && d < NCT; ++j) {
                const int e = (int)src[j];
                dst[d++] = (unsigned short)e;
                dsum += loadf(hewi, e, isf32);       // once per membership entry
            }
        }
        ndeg[v] = d;
        dinv[v] = dsum > 0.f ? 1.f / dsum : 0.f;
        for (int j = d; j < NCT; ++j) dst[j] = 0;
    }
}

// ---- edge_agg: edge_x[e][t*64+f] = (1/deg) * sum_{v in e} xh16[v][f*4+t] -------
// wave per edge; half-wave per 4-member chunk (ushort4 index load ->
// 4 independent 16B/lane row loads in flight), shfl_xor(32) combine
__global__ void edge_agg_kernel(const unsigned short* __restrict__ xh16,
                                const int* __restrict__ edeg,
                                const unsigned short* __restrict__ ect,
                                unsigned short* __restrict__ edge_x) {
    const int wid = threadIdx.x >> 6, lane = threadIdx.x & 63;
    const int e = blockIdx.x * 4 + wid;
    const int half = lane >> 5, sl = lane & 31;
    const int deg = edeg[e];
    const unsigned short* lst = ect + (size_t)e * ECT;
    float a[8] = {0.f, 0.f, 0.f, 0.f, 0.f, 0.f, 0.f, 0.f};
    for (int j0 = half * 4; j0 < deg; j0 += 8) {
        const ushort4 il = *(const ushort4*)(lst + j0);   // 4 indices, one 8B load
        const int4 u0 = *(const int4*)(xh16 + (size_t)il.x * 256 + sl * 8);
        const int4 u1 = *(const int4*)(xh16 + (size_t)il.y * 256 + sl * 8);
        const int4 u2 = *(const int4*)(xh16 + (size_t)il.z * 256 + sl * 8);
        const int4 u3 = *(const int4*)(xh16 + (size_t)il.w * 256 + sl * 8);
        acc8_h(u0, a);                                    // j0 < deg by loop cond
        if (j0 + 1 < deg) acc8_h(u1, a);
        if (j0 + 2 < deg) acc8_h(u2, a);
        if (j0 + 3 < deg) acc8_h(u3, a);
    }
    #pragma unroll
    for (int k = 0; k < 8; ++k) a[k] += __shfl_xor(a[k], 32);
    const float binv = deg > 0 ? 1.f / (float)deg : 0.f;
    if (lane < 32) {
        // lane holds halfwords h = sl*8+k of x-layout: f = 2*sl + (k>>2), t = k&3
        unsigned short* row = edge_x + (size_t)e * 256;
        #pragma unroll
        for (int t = 0; t < 4; ++t) {
            unsigned pk = (unsigned)f2h(a[t] * binv)
                        | ((unsigned)f2h(a[4 + t] * binv) << 16);
            *(unsigned*)(row + t * 64 + sl * 2) = pk;   // t-major transpose
        }
    }
}

// ---- node_gemm: per wave 4 nodes -> 16x64 A-tile -> 16x16x32 f16 MFMA x W ------
// D^-1 precomputed by compact; gather with 4-deep ILP like edge_agg
__global__ __launch_bounds__(256) void node_gemm_kernel(
        const int* __restrict__ he, const unsigned short* __restrict__ xdet,
        const unsigned short* __restrict__ edge_x,
        const int* __restrict__ ndeg, const unsigned short* __restrict__ nct,
        const float* __restrict__ dinv,
        const void* __restrict__ W, const void* __restrict__ bias,
        void* __restrict__ out) {
    __shared__ __align__(16) unsigned short wt[64 * 72];        // W^T [o][f], pad 72
    __shared__ __align__(16) unsigned short atile[4][16 * 72];  // per-wave A tile
    __shared__ float lbias[64];
    __shared__ int lflag[2];
    int is64, isf32;
    detect_flags(he, xdet, is64, isf32, lflag);
    (void)is64;
    const int tid = threadIdx.x, wid = tid >> 6, lane = tid & 63;
    const int quad = lane >> 4, l15 = lane & 15;
    const int half = lane >> 5, sl = lane & 31;

    #pragma unroll
    for (int k = 0; k < 16; ++k) {                // stage W^T once per block (fp16)
        int idx = tid + k * 256;                  // f = idx>>6, o = idx&63
        wt[(idx & 63) * 72 + (idx >> 6)] = f2h(loadf(W, idx, isf32));
    }
    if (tid < 64) lbias[tid] = loadf(bias, tid, isf32);

    const int tile = blockIdx.x * 4 + wid;        // 16 A-rows = 4 nodes
    for (int r = 0; r < 4; ++r) {
        const int v = tile * 4 + r;
        const int deg = ndeg[v];
        const float s = dinv[v];                  // D^-1 (GEMM is linear)
        const unsigned short* lst = nct + (size_t)v * NCT;
        float a[8] = {0.f, 0.f, 0.f, 0.f, 0.f, 0.f, 0.f, 0.f};
        for (int j0 = half * 4; j0 < deg; j0 += 8) {
            const ushort4 il = *(const ushort4*)(lst + j0);
            const int4 u0 = *(const int4*)(edge_x + (size_t)il.x * 256 + sl * 8);
            const int4 u1 = *(const int4*)(edge_x + (size_t)il.y * 256 + sl * 8);
            const int4 u2 = *(const int4*)(edge_x + (size_t)il.z * 256 + sl * 8);
            const int4 u3 = *(const int4*)(edge_x + (size_t)il.w * 256 + sl * 8);
            acc8_h(u0, a);
            if (j0 + 1 < deg) acc8_h(u1, a);
            if (j0 + 2 < deg) acc8_h(u2, a);
            if (j0 + 3 < deg) acc8_h(u3, a);
        }
        #pragma unroll
        for (int k = 0; k < 8; ++k) a[k] += __shfl_xor(a[k], 32);
        if (lane < 32) {
            // t-major row halfwords h=sl*8+k: t = sl>>3, f = (sl&7)*8 + k
            unsigned short pk[8];
            #pragma unroll
            for (int k = 0; k < 8; ++k) pk[k] = f2h(a[k] * s);
            *(int4*)&atile[wid][(r * 4 + (sl >> 3)) * 72 + (sl & 7) * 8] =
                *(int4*)pk;
        }
    }
    __syncthreads();

    v8h bfr[4][2];                                // B frags: lane holds B[k][n]
    #pragma unroll
    for (int j = 0; j < 4; ++j)
        #pragma unroll
        for (int kk = 0; kk < 2; ++kk)
            bfr[j][kk] = *(v8h*)&wt[(j * 16 + l15) * 72 + quad * 8 + kk * 32];
    // A frags: lane holds A[m=lane&15][k=quad*8+j]
    v8h af0 = *(v8h*)&atile[wid][l15 * 72 + quad * 8];
    v8h af1 = *(v8h*)&atile[wid][l15 * 72 + quad * 8 + 32];

    const int node = tile * 4 + quad;             // C row = quad*4+reg -> t=reg
    #pragma unroll
    for (int j = 0; j < 4; ++j) {
        v4f acc = {0.f, 0.f, 0.f, 0.f};
        acc = __builtin_amdgcn_mfma_f32_16x16x32_f16(af0, bfr[j][0], acc, 0, 0, 0);
        acc = __builtin_amdgcn_mfma_f32_16x16x32_f16(af1, bfr[j][1], acc, 0, 0, 0);
        const int o = j * 16 + l15;
        const float bv = lbias[o];
        float r0 = acc[0] + bv, r1 = acc[1] + bv, r2 = acc[2] + bv, r3 = acc[3] + bv;
        r0 = r0 > 0.f ? r0 : 0.f; r1 = r1 > 0.f ? r1 : 0.f;
        r2 = r2 > 0.f ? r2 : 0.f; r3 = r3 > 0.f ? r3 : 0.f;
        if (isf32) {
            float4 f4 = { r0, r1, r2, r3 };       // out[node][o][t], t=0..3
            *(float4*)((float*)out + (size_t)node * 256 + o * 4) = f4;
        } else {
            ushort4 pk = { f2bf(r0), f2bf(r1), f2bf(r2), f2bf(r3) };
            *(ushort4*)((unsigned short*)out + (size_t)node * 256 + o * 4) = pk;
        }
    }
}

extern "C" void kernel_launch(void* const* d_in, const int* in_sizes, int n_in,
                              void* d_out, int out_size, void* d_ws, size_t ws_size,
                              hipStream_t stream) {
    const void* x    = d_in[0];
    const int*  he   = (const int*)d_in[1];   // [2,NNZ] int32 or int64 (detected)
    const void* hewi = d_in[2];
    const void* W    = d_in[3];
    const void* bias = d_in[4];

    // ---- workspace layout (word offsets); harness provides >= 102.6MB ----------
    float* ws = (float*)d_ws;
    unsigned short* edge_x = (unsigned short*)ws;            // 5.12M hw = 2,560,000 w
    int*   ecnt8 = (int*)(ws + 2560000);                     //   160,000 w (8x20000)
    int*   ncnt8 = (int*)(ws + 2720000);                     //   320,000 w (8x40000)
    unsigned short* elst8 = (unsigned short*)(ws + 3040000); // 3.2M hw = 1,600,000 w
    unsigned short* nlst8 = (unsigned short*)(ws + 4640000); // 4.48M hw = 2,240,000 w
    unsigned short* xh16  = (unsigned short*)(ws + 6880000); // 10.24M hw = 5,120,000 w
    unsigned short* ect   = (unsigned short*)(ws + 12000000);//  1.28M hw =   640,000 w
    unsigned short* nct   = (unsigned short*)(ws + 12640000);//  1.28M hw =   640,000 w
    int*   edeg = (int*)(ws + 13280000);                     //    20,000 w
    int*   ndeg = (int*)(ws + 13300000);                     //    40,000 w
    float* dinv = (float*)(ws + 13340000);                   //    40,000 w
    if (ws_size < (size_t)13400000 * 4) return;              // 53.6MB; clean signal

    // zero privatized counters (contiguous 480,000 words)
    hipMemsetAsync(ecnt8, 0, (size_t)480000 * 4, stream);

    convert_build_kernel<<<CVT_BLOCKS + (NNZV + 255) / 256, 256, 0, stream>>>(
        he, x, ecnt8, ncnt8, elst8, nlst8, xh16);
    compact_kernel<<<(NUM_EDGES + NUM_NODES + 255) / 256, 256, 0, stream>>>(
        he, (const unsigned short*)x, hewi, ecnt8, elst8, ncnt8, nlst8,
        ect, nct, edeg, ndeg, dinv);
    edge_agg_kernel<<<NUM_EDGES / 4, 256, 0, stream>>>(
        xh16, edeg, ect, edge_x);
    node_gemm_kernel<<<NUM_NODES / 16, 256, 0, stream>>>(
        he, (const unsigned short*)x, edge_x, ndeg, nct, dinv, W, bias, d_out);
}